// Round 6
// baseline (1250.348 us; speedup 1.0000x reference)
//
#include <hip/hip_runtime.h>
#include <hip/hip_fp16.h>
#include <hip/hip_bf16.h>

// Problem constants (fixed by reference setup_inputs):
//   u_predict: [B=64][NL=2048][NH=32][D=16] f32  (256 MB)
//   b:         [NL=2048][NH=32] f32
//   out v:     [B=64][NH=32][D=16] f32
#define B_  64
#define NL_ 2048
#define NH_ 32
#define D_  16
#define HD_ 512              // NH_*D_
#define LCHUNK 64            // l's per block
#define NCHUNK (NL_/LCHUNK)  // 32

typedef float        f32x4 __attribute__((ext_vector_type(4)));
typedef unsigned int u32x4 __attribute__((ext_vector_type(4)));

union H8 { u32x4 u4; __half2 h2[4]; };
union F4 { f32x4 v;  float f[4]; };

// ---- fused squash tail: last block per b reduces partials, squashes, updates vsum/out.
// MODE 0: vsum = v;  MODE 1: vsum += v;  MODE 2: out = v.
template<int MODE>
__device__ __forceinline__ void fused_squash(int b, int tid,
                                             int* __restrict__ ctr,
                                             const float* __restrict__ partial_s,
                                             float* __restrict__ vsum,
                                             float* __restrict__ out)
{
    __shared__ int isLast;
    __syncthreads();
    __threadfence();                       // make this block's partial writes visible
    if (tid == 0) {
        const int old = atomicAdd(ctr + b, 1);   // device-scope by default
        isLast = (old == NCHUNK - 1) ? 1 : 0;
    }
    __syncthreads();
    if (!isLast) return;
    __threadfence();                       // acquire: see all 32 blocks' partials

    const float* p = partial_s + (size_t)b*NCHUNK*HD_;
    float s0 = 0.f, s1 = 0.f;
    #pragma unroll
    for (int c = 0; c < NCHUNK; ++c) {
        s0 += p[c*HD_ + tid];
        s1 += p[c*HD_ + tid + 256];
    }
    // ||s||^2 over d=16 (16 consecutive lanes share h)
    float q0 = s0*s0, q1 = s1*s1;
    q0 += __shfl_xor(q0,1); q0 += __shfl_xor(q0,2); q0 += __shfl_xor(q0,4); q0 += __shfl_xor(q0,8);
    q1 += __shfl_xor(q1,1); q1 += __shfl_xor(q1,2); q1 += __shfl_xor(q1,4); q1 += __shfl_xor(q1,8);
    const float v0 = s0 * (q0 / ((1.f + q0) * sqrtf(q0 + 1e-8f)));
    const float v1 = s1 * (q1 / ((1.f + q1) * sqrtf(q1 + 1e-8f)));

    if (MODE == 0)      { vsum[b*HD_+tid] = v0;  vsum[b*HD_+tid+256] = v1;  }
    else if (MODE == 1) { vsum[b*HD_+tid] += v0; vsum[b*HD_+tid+256] += v1; }
    else                { out[b*HD_+tid] = v0;   out[b*HD_+tid+256]  = v1;  }
}

// ---------------- c0 kernel: c0 = softmax(blog) over h; block 0 zeroes the counters --
__global__ __launch_bounds__(256) void c0_kernel(const float* __restrict__ blog,
                                                 float* __restrict__ c0,
                                                 int* __restrict__ ctr)
{
    if (blockIdx.x == 0 && threadIdx.x < 4*B_) ctr[threadIdx.x] = 0;
    const int tid = threadIdx.x;
    const int l   = blockIdx.x*8 + (tid >> 5);
    const int h   = tid & 31;
    float x = blog[l*NH_ + h];
    float m = x;
    #pragma unroll
    for (int off = 1; off < 32; off <<= 1) m = fmaxf(m, __shfl_xor(m, off));
    float e = __expf(x - m);
    float s = e;
    #pragma unroll
    for (int off = 1; off < 32; off <<= 1) s += __shfl_xor(s, off);
    c0[l*NH_ + h] = e / s;
}

// ---------------- pass 0: f32 read (nt), weighted sum with precomputed c0, emit fp16 --
__global__ __launch_bounds__(256) void pass0_kernel(const float* __restrict__ u,
                                                    const float* __restrict__ c0,
                                                    __half* __restrict__ u16,
                                                    float* __restrict__ partial_s,
                                                    float* __restrict__ vsum,
                                                    float* __restrict__ out,
                                                    int* __restrict__ ctr)
{
    const int b     = blockIdx.y;
    const int chunk = blockIdx.x;
    const int tid   = threadIdx.x;
    const int wave  = tid >> 6;
    const int lane  = tid & 63;
    const int h0    = lane >> 2;          // 0..15
    const int h1    = h0 + 16;

    float4 accA = {0.f,0.f,0.f,0.f};
    float4 accB = {0.f,0.f,0.f,0.f};

    const int l0 = chunk*LCHUNK + wave*(LCHUNK/4);

    for (int j = 0; j < LCHUNK/4; ++j) {
        const int l = l0 + j;
        const size_t base = ((size_t)b*NL_ + l)*HD_;
        F4 a, bq;
        a.v  = __builtin_nontemporal_load((const f32x4*)(u + base + 4*lane));
        bq.v = __builtin_nontemporal_load((const f32x4*)(u + base + 256 + 4*lane));

        union { uint2 u2; __half2 h2[2]; } ha, hb;
        ha.h2[0] = __floats2half2_rn(a.f[0], a.f[1]);   ha.h2[1] = __floats2half2_rn(a.f[2], a.f[3]);
        hb.h2[0] = __floats2half2_rn(bq.f[0], bq.f[1]); hb.h2[1] = __floats2half2_rn(bq.f[2], bq.f[3]);
        *(uint2*)((__half*)u16 + base + 4*lane)       = ha.u2;
        *(uint2*)((__half*)u16 + base + 256 + 4*lane) = hb.u2;

        const float ca = c0[l*NH_ + h0];
        const float cb = c0[l*NH_ + h1];

        accA.x += ca*a.f[0];  accA.y += ca*a.f[1];  accA.z += ca*a.f[2];  accA.w += ca*a.f[3];
        accB.x += cb*bq.f[0]; accB.y += cb*bq.f[1]; accB.z += cb*bq.f[2]; accB.w += cb*bq.f[3];
    }

    __shared__ float sred[4][HD_];
    float* dst = &sred[wave][0];
    dst[4*lane+0]     = accA.x; dst[4*lane+1]     = accA.y;
    dst[4*lane+2]     = accA.z; dst[4*lane+3]     = accA.w;
    dst[256+4*lane+0] = accB.x; dst[256+4*lane+1] = accB.y;
    dst[256+4*lane+2] = accB.z; dst[256+4*lane+3] = accB.w;
    __syncthreads();

    float r0 = sred[0][tid]     + sred[1][tid]     + sred[2][tid]     + sred[3][tid];
    float r1 = sred[0][tid+256] + sred[1][tid+256] + sred[2][tid+256] + sred[3][tid+256];
    float* pout = partial_s + ((size_t)b*NCHUNK + chunk)*HD_;
    pout[tid]       = r0;
    pout[tid + 256] = r1;

    fused_squash<0>(b, tid, ctr, partial_s, vsum, out);
}

// ---------------- fp16 routing pass: lane owns full h (16 d's), 2 l's per wave-iter ---
template<int MODE, bool LAST>
__global__ __launch_bounds__(256) void pass16_kernel(const __half* __restrict__ u16,
                                                     const float* __restrict__ blog,
                                                     float* __restrict__ vsum,
                                                     float* __restrict__ partial_s,
                                                     float* __restrict__ out,
                                                     int* __restrict__ ctr)
{
    const int b     = blockIdx.y;
    const int chunk = blockIdx.x;
    const int tid   = threadIdx.x;
    const int wave  = tid >> 6;
    const int lane  = tid & 63;
    const int hh    = lane & 31;
    const int lpar  = lane >> 5;

    float vs[16];
    #pragma unroll
    for (int q = 0; q < 4; ++q) {
        const float4 t = *(const float4*)(vsum + b*HD_ + hh*D_ + 4*q);
        vs[4*q+0] = t.x; vs[4*q+1] = t.y; vs[4*q+2] = t.z; vs[4*q+3] = t.w;
    }

    float acc[16];
    #pragma unroll
    for (int d = 0; d < 16; ++d) acc[d] = 0.f;

    const int lbase = chunk*LCHUNK + wave*(LCHUNK/4);   // 16 l's per wave

    for (int j = 0; j < LCHUNK/8; ++j) {                // 8 iters, 2 l's each
        const int l = lbase + 2*j + lpar;
        const size_t base = ((size_t)b*NL_ + l)*HD_ + hh*D_;
        H8 x0, x1;
        if (LAST) {
            x0.u4 = __builtin_nontemporal_load((const u32x4*)(u16 + base));
            x1.u4 = __builtin_nontemporal_load((const u32x4*)(u16 + base + 8));
        } else {
            x0.u4 = *(const u32x4*)(u16 + base);
            x1.u4 = *(const u32x4*)(u16 + base + 8);
        }
        float f[16];
        #pragma unroll
        for (int q = 0; q < 4; ++q) {
            const float2 t0 = __half22float2(x0.h2[q]);
            const float2 t1 = __half22float2(x1.h2[q]);
            f[2*q+0] = t0.x; f[2*q+1] = t0.y;
            f[8+2*q+0] = t1.x; f[8+2*q+1] = t1.y;
        }

        float dot = 0.f;
        #pragma unroll
        for (int d = 0; d < 16; ++d) dot = __fmaf_rn(f[d], vs[d], dot);

        const float la = fminf(blog[l*NH_ + hh] + dot, 80.f);
        const float e  = __expf(la);
        float ssum = e;
        #pragma unroll
        for (int off = 1; off < 32; off <<= 1) ssum += __shfl_xor(ssum, off);
        const float c = e / ssum;

        #pragma unroll
        for (int d = 0; d < 16; ++d) acc[d] = __fmaf_rn(c, f[d], acc[d]);
    }

    __shared__ float sred[4][2][NH_][D_];
    float* dst = &sred[wave][lpar][hh][0];
    #pragma unroll
    for (int q = 0; q < 4; ++q) {
        float4 t = { acc[4*q+0], acc[4*q+1], acc[4*q+2], acc[4*q+3] };
        *(float4*)(dst + 4*q) = t;
    }
    __syncthreads();

    const float* sp = &sred[0][0][0][0];
    float r0 = 0.f, r1 = 0.f;
    #pragma unroll
    for (int w = 0; w < 4; ++w) {
        #pragma unroll
        for (int p = 0; p < 2; ++p) {
            r0 += sp[w*1024 + p*512 + tid];
            r1 += sp[w*1024 + p*512 + tid + 256];
        }
    }
    float* pout = partial_s + ((size_t)b*NCHUNK + chunk)*HD_;
    pout[tid]       = r0;
    pout[tid + 256] = r1;

    fused_squash<MODE>(b, tid, ctr, partial_s, vsum, out);
}

// ---------------- fallback f32 routing pass (round-1 proven path) ---------------------
template<bool ADD_DOT>
__global__ __launch_bounds__(256) void pass_kernel(const float* __restrict__ u,
                                                   const float* __restrict__ blog,
                                                   const float* __restrict__ vsum,
                                                   float* __restrict__ partial_s)
{
    const int b     = blockIdx.y;
    const int chunk = blockIdx.x;
    const int tid   = threadIdx.x;
    const int wave  = tid >> 6;
    const int lane  = tid & 63;
    const int h0    = lane >> 2;
    const int h1    = h0 + 16;
    const int dq    = (lane & 3) << 2;

    float4 vA = {0.f,0.f,0.f,0.f}, vB = {0.f,0.f,0.f,0.f};
    if (ADD_DOT) {
        vA = *(const float4*)(vsum + b*HD_ + h0*D_ + dq);
        vB = *(const float4*)(vsum + b*HD_ + h1*D_ + dq);
    }

    float4 accA = {0.f,0.f,0.f,0.f};
    float4 accB = {0.f,0.f,0.f,0.f};
    const int l0 = chunk*LCHUNK + wave*(LCHUNK/4);

    for (int j = 0; j < LCHUNK/4; ++j) {
        const int l = l0 + j;
        const float* up = u + ((size_t)b*NL_ + l)*HD_;
        const float4 a  = *(const float4*)(up + 4*lane);
        const float4 bq = *(const float4*)(up + 256 + 4*lane);

        float la = blog[l*NH_ + h0];
        float lb = blog[l*NH_ + h1];

        if (ADD_DOT) {
            float da = a.x*vA.x + a.y*vA.y + a.z*vA.z + a.w*vA.w;
            float db = bq.x*vB.x + bq.y*vB.y + bq.z*vB.z + bq.w*vB.w;
            da += __shfl_xor(da, 1); da += __shfl_xor(da, 2);
            db += __shfl_xor(db, 1); db += __shfl_xor(db, 2);
            la += da; lb += db;
        }

        float m = fmaxf(la, lb);
        #pragma unroll
        for (int off = 4; off < 64; off <<= 1) m = fmaxf(m, __shfl_xor(m, off));
        const float ea = __expf(la - m);
        const float eb = __expf(lb - m);
        float ssum = ea + eb;
        #pragma unroll
        for (int off = 4; off < 64; off <<= 1) ssum += __shfl_xor(ssum, off);
        const float inv = 1.0f / ssum;
        const float ca = ea * inv;
        const float cb = eb * inv;

        accA.x += ca*a.x;  accA.y += ca*a.y;  accA.z += ca*a.z;  accA.w += ca*a.w;
        accB.x += cb*bq.x; accB.y += cb*bq.y; accB.z += cb*bq.z; accB.w += cb*bq.w;
    }

    __shared__ float sred[4][HD_];
    float* dst = &sred[wave][0];
    dst[4*lane+0]     = accA.x; dst[4*lane+1]     = accA.y;
    dst[4*lane+2]     = accA.z; dst[4*lane+3]     = accA.w;
    dst[256+4*lane+0] = accB.x; dst[256+4*lane+1] = accB.y;
    dst[256+4*lane+2] = accB.z; dst[256+4*lane+3] = accB.w;
    __syncthreads();

    float r0 = sred[0][tid]     + sred[1][tid]     + sred[2][tid]     + sred[3][tid];
    float r1 = sred[0][tid+256] + sred[1][tid+256] + sred[2][tid+256] + sred[3][tid+256];
    float* pout = partial_s + ((size_t)b*NCHUNK + chunk)*HD_;
    pout[tid]       = r0;
    pout[tid + 256] = r1;
}

// ---------------- standalone squash (fallback path only) ------------------------------
template<int MODE>
__global__ __launch_bounds__(512) void squash_kernel(const float* __restrict__ partial_s,
                                                     float* __restrict__ vsum,
                                                     float* __restrict__ out)
{
    const int b = blockIdx.x;
    const int t = threadIdx.x;
    const float* p = partial_s + (size_t)b*NCHUNK*HD_ + t;
    float s = 0.f;
    #pragma unroll
    for (int c = 0; c < NCHUNK; ++c) s += p[c*HD_];

    float sq = s*s;
    sq += __shfl_xor(sq, 1); sq += __shfl_xor(sq, 2);
    sq += __shfl_xor(sq, 4); sq += __shfl_xor(sq, 8);

    const float scale = sq / ((1.0f + sq) * sqrtf(sq + 1e-8f));
    const float v = s * scale;

    if (MODE == 0)      vsum[b*HD_ + t]  = v;
    else if (MODE == 1) vsum[b*HD_ + t] += v;
    else                out[b*HD_ + t]   = v;
}

extern "C" void kernel_launch(void* const* d_in, const int* in_sizes, int n_in,
                              void* d_out, int out_size, void* d_ws, size_t ws_size,
                              hipStream_t stream)
{
    const float* u    = (const float*)d_in[0];   // [64][2048][32][16]
    const float* blog = (const float*)d_in[1];   // [2048][32]
    float* out        = (float*)d_out;           // [64][32][16]

    // ws layout: [partials 4MB][vsum 128KB][c0 256KB][ctr 1KB][u16 128MB]
    float*  partial_s = (float*)d_ws;
    float*  vsum      = partial_s + (size_t)B_*NCHUNK*HD_;
    float*  c0        = vsum + (size_t)B_*HD_;
    int*    ctr       = (int*)(c0 + (size_t)NL_*NH_);
    __half* u16       = (__half*)(ctr + 256);
    const size_t need = ((size_t)B_*NCHUNK*HD_ + (size_t)B_*HD_ + (size_t)NL_*NH_)*sizeof(float)
                      + 256*sizeof(int)
                      + (size_t)B_*NL_*HD_*sizeof(__half);

    dim3 grid(NCHUNK, B_);
    dim3 block(256);

    if (ws_size >= need) {
        c0_kernel<<<NL_/8, 256, 0, stream>>>(blog, c0, ctr);
        pass0_kernel<<<grid, block, 0, stream>>>(u, c0, u16, partial_s, vsum, out, ctr);
        pass16_kernel<1,false><<<grid, block, 0, stream>>>(u16, blog, vsum, partial_s, out, ctr + 1*B_);
        pass16_kernel<1,false><<<grid, block, 0, stream>>>(u16, blog, vsum, partial_s, out, ctr + 2*B_);
        pass16_kernel<2,true ><<<grid, block, 0, stream>>>(u16, blog, vsum, partial_s, out, ctr + 3*B_);
    } else {
        pass_kernel<false><<<grid, block, 0, stream>>>(u, blog, vsum, partial_s);
        squash_kernel<0><<<B_, 512, 0, stream>>>(partial_s, vsum, out);

        pass_kernel<true><<<grid, block, 0, stream>>>(u, blog, vsum, partial_s);
        squash_kernel<1><<<B_, 512, 0, stream>>>(partial_s, vsum, out);

        pass_kernel<true><<<grid, block, 0, stream>>>(u, blog, vsum, partial_s);
        squash_kernel<1><<<B_, 512, 0, stream>>>(partial_s, vsum, out);

        pass_kernel<true><<<grid, block, 0, stream>>>(u, blog, vsum, partial_s);
        squash_kernel<2><<<B_, 512, 0, stream>>>(partial_s, vsum, out);
    }
}

// Round 7
// 156.426 us; speedup vs baseline: 7.9932x; 7.9932x over previous
//
#include <hip/hip_runtime.h>
#include <hip/hip_fp16.h>
#include <hip/hip_bf16.h>

// Problem constants (fixed by reference setup_inputs):
//   u_predict: [B=64][NL=2048][NH=32][D=16] f32  (256 MB)
//   b:         [NL=2048][NH=32] f32
//   out v:     [B=64][NH=32][D=16] f32
#define B_  64
#define NL_ 2048
#define NH_ 32
#define D_  16
#define HD_ 512              // NH_*D_
#define LCH 128              // l's per block (fp16 path)
#define NCH (NL_/LCH)        // 16

typedef float        f32x4 __attribute__((ext_vector_type(4)));
typedef unsigned int u32x4 __attribute__((ext_vector_type(4)));

union H8 { u32x4 u4; __half2 h2[4]; };
union F4 { f32x4 v;  float f[4]; };

// ---------------- pass 0: fused softmax(b) (LDS), f32 nt-read, weighted sum, emit fp16
__global__ __launch_bounds__(256) void pass0_kernel(const float* __restrict__ u,
                                                    const float* __restrict__ blog,
                                                    __half* __restrict__ u16,
                                                    float* __restrict__ part_out)
{
    const int b     = blockIdx.y;
    const int chunk = blockIdx.x;
    const int tid   = threadIdx.x;
    const int wave  = tid >> 6;
    const int lane  = tid & 63;
    const int h0    = lane >> 2;          // 0..15
    const int h1    = h0 + 16;
    const int lbase = chunk*LCH;

    // --- fused c0 = softmax(blog) for this block's 128 l's ---
    __shared__ float c0s[LCH][NH_];       // 16 KB
    {
        const int g = tid >> 5, l32 = tid & 31;
        for (int i = g; i < LCH; i += 8) {
            float x = blog[(lbase+i)*NH_ + l32];
            float m = x;
            #pragma unroll
            for (int off = 1; off < 32; off <<= 1) m = fmaxf(m, __shfl_xor(m, off));
            const float e = __expf(x - m);
            float s = e;
            #pragma unroll
            for (int off = 1; off < 32; off <<= 1) s += __shfl_xor(s, off);
            c0s[i][l32] = e / s;
        }
    }
    __syncthreads();

    float4 accA = {0.f,0.f,0.f,0.f};
    float4 accB = {0.f,0.f,0.f,0.f};

    const int l0 = lbase + wave*(LCH/4);  // 32 l's per wave

    for (int j = 0; j < LCH/4; ++j) {
        const int l = l0 + j;
        const size_t base = ((size_t)b*NL_ + l)*HD_;
        F4 a, bq;
        a.v  = __builtin_nontemporal_load((const f32x4*)(u + base + 4*lane));
        bq.v = __builtin_nontemporal_load((const f32x4*)(u + base + 256 + 4*lane));

        union { uint2 u2; __half2 h2[2]; } ha, hb;
        ha.h2[0] = __floats2half2_rn(a.f[0], a.f[1]);   ha.h2[1] = __floats2half2_rn(a.f[2], a.f[3]);
        hb.h2[0] = __floats2half2_rn(bq.f[0], bq.f[1]); hb.h2[1] = __floats2half2_rn(bq.f[2], bq.f[3]);
        *(uint2*)((__half*)u16 + base + 4*lane)       = ha.u2;
        *(uint2*)((__half*)u16 + base + 256 + 4*lane) = hb.u2;

        const float ca = c0s[l - lbase][h0];
        const float cb = c0s[l - lbase][h1];

        accA.x += ca*a.f[0];  accA.y += ca*a.f[1];  accA.z += ca*a.f[2];  accA.w += ca*a.f[3];
        accB.x += cb*bq.f[0]; accB.y += cb*bq.f[1]; accB.z += cb*bq.f[2]; accB.w += cb*bq.f[3];
    }

    __shared__ float sred[4][HD_];        // 8 KB
    float* dst = &sred[wave][0];
    dst[4*lane+0]     = accA.x; dst[4*lane+1]     = accA.y;
    dst[4*lane+2]     = accA.z; dst[4*lane+3]     = accA.w;
    dst[256+4*lane+0] = accB.x; dst[256+4*lane+1] = accB.y;
    dst[256+4*lane+2] = accB.z; dst[256+4*lane+3] = accB.w;
    __syncthreads();

    float r0 = sred[0][tid]     + sred[1][tid]     + sred[2][tid]     + sred[3][tid];
    float r1 = sred[0][tid+256] + sred[1][tid+256] + sred[2][tid+256] + sred[3][tid+256];
    float* pout = part_out + ((size_t)b*NCH + chunk)*HD_;
    pout[tid]       = r0;
    pout[tid + 256] = r1;
}

// ---------------- fp16 routing pass with fused squash-at-head ------------------------
// Head: every block reduces part_in (prev pass) -> v, adds prior vsum (ITER>=2),
// chunk==0 persists the accumulated vsum for the next pass. No fences needed:
// ordering comes from the kernel boundary; part ping-pong avoids aliasing.
template<int ITER>   // 1,2,3
__global__ __launch_bounds__(256) void pass16_kernel(const __half* __restrict__ u16,
                                                     const float* __restrict__ blog,
                                                     const float* __restrict__ vsumG_in,
                                                     float* __restrict__ vsumG_out,
                                                     const float* __restrict__ part_in,
                                                     float* __restrict__ part_out)
{
    const int b     = blockIdx.y;
    const int chunk = blockIdx.x;
    const int tid   = threadIdx.x;
    const int wave  = tid >> 6;
    const int lane  = tid & 63;
    const int hh    = lane & 31;
    const int lpar  = lane >> 5;

    __shared__ float smem[4*2*NH_*D_];    // 16 KB; first 512 floats double as vsl
    float* vsl = smem;

    // --- fused squash head ---
    {
        const float* pin = part_in + (size_t)b*NCH*HD_;
        float s0 = 0.f, s1 = 0.f;
        #pragma unroll
        for (int c = 0; c < NCH; ++c) { s0 += pin[c*HD_ + tid]; s1 += pin[c*HD_ + tid + 256]; }
        float q0 = s0*s0, q1 = s1*s1;
        q0 += __shfl_xor(q0,1); q0 += __shfl_xor(q0,2); q0 += __shfl_xor(q0,4); q0 += __shfl_xor(q0,8);
        q1 += __shfl_xor(q1,1); q1 += __shfl_xor(q1,2); q1 += __shfl_xor(q1,4); q1 += __shfl_xor(q1,8);
        float v0 = s0 * (q0 / ((1.f + q0) * sqrtf(q0 + 1e-8f)));
        float v1 = s1 * (q1 / ((1.f + q1) * sqrtf(q1 + 1e-8f)));
        if (ITER >= 2) { v0 += vsumG_in[b*HD_ + tid]; v1 += vsumG_in[b*HD_ + tid + 256]; }
        if (ITER <= 2 && chunk == 0) { vsumG_out[b*HD_ + tid] = v0; vsumG_out[b*HD_ + tid + 256] = v1; }
        vsl[tid] = v0; vsl[tid + 256] = v1;
    }
    __syncthreads();

    float vs[16];
    #pragma unroll
    for (int q = 0; q < 16; ++q) vs[q] = vsl[hh*D_ + q];
    __syncthreads();   // all reads of vsl done before smem is reused for sred

    float acc[16];
    #pragma unroll
    for (int d = 0; d < 16; ++d) acc[d] = 0.f;

    const int lbase = chunk*LCH + wave*(LCH/4);     // 32 l's per wave

    for (int j = 0; j < LCH/8; ++j) {               // 16 iters, 2 l's each
        const int l = lbase + 2*j + lpar;
        const size_t base = ((size_t)b*NL_ + l)*HD_ + hh*D_;
        H8 x0, x1;
        if (ITER == 3) {
            x0.u4 = __builtin_nontemporal_load((const u32x4*)(u16 + base));
            x1.u4 = __builtin_nontemporal_load((const u32x4*)(u16 + base + 8));
        } else {
            x0.u4 = *(const u32x4*)(u16 + base);
            x1.u4 = *(const u32x4*)(u16 + base + 8);
        }
        float f[16];
        #pragma unroll
        for (int q = 0; q < 4; ++q) {
            const float2 t0 = __half22float2(x0.h2[q]);
            const float2 t1 = __half22float2(x1.h2[q]);
            f[2*q+0] = t0.x; f[2*q+1] = t0.y;
            f[8+2*q+0] = t1.x; f[8+2*q+1] = t1.y;
        }

        float dot = 0.f;
        #pragma unroll
        for (int d = 0; d < 16; ++d) dot = __fmaf_rn(f[d], vs[d], dot);

        const float la = fminf(blog[l*NH_ + hh] + dot, 80.f);
        const float e  = __expf(la);
        float ssum = e;
        #pragma unroll
        for (int off = 1; off < 32; off <<= 1) ssum += __shfl_xor(ssum, off);
        const float c = e / ssum;

        #pragma unroll
        for (int d = 0; d < 16; ++d) acc[d] = __fmaf_rn(c, f[d], acc[d]);
    }

    // block reduce: smem as [wave][lpar][hh][d]
    float* dst = smem + ((wave*2 + lpar)*NH_ + hh)*D_;
    #pragma unroll
    for (int q = 0; q < 4; ++q) {
        float4 t = { acc[4*q+0], acc[4*q+1], acc[4*q+2], acc[4*q+3] };
        *(float4*)(dst + 4*q) = t;
    }
    __syncthreads();

    float r0 = 0.f, r1 = 0.f;
    #pragma unroll
    for (int w = 0; w < 8; ++w) {
        r0 += smem[w*512 + tid];
        r1 += smem[w*512 + tid + 256];
    }
    float* pout = part_out + ((size_t)b*NCH + chunk)*HD_;
    pout[tid]       = r0;
    pout[tid + 256] = r1;
}

// ---------------- final squash: reduce partials, squash, write d_out ------------------
__global__ __launch_bounds__(512) void squash_final(const float* __restrict__ part_in,
                                                    float* __restrict__ out)
{
    const int b = blockIdx.x;
    const int t = threadIdx.x;
    const float* p = part_in + (size_t)b*NCH*HD_ + t;
    float s = 0.f;
    #pragma unroll
    for (int c = 0; c < NCH; ++c) s += p[c*HD_];

    float sq = s*s;
    sq += __shfl_xor(sq, 1); sq += __shfl_xor(sq, 2);
    sq += __shfl_xor(sq, 4); sq += __shfl_xor(sq, 8);

    out[b*HD_ + t] = s * (sq / ((1.0f + sq) * sqrtf(sq + 1e-8f)));
}

// ---------------- fallback f32 path (round-1 proven; used only if ws too small) -------
#define FB_LCH 64
#define FB_NCH 32
template<bool ADD_DOT>
__global__ __launch_bounds__(256) void pass_kernel(const float* __restrict__ u,
                                                   const float* __restrict__ blog,
                                                   const float* __restrict__ vsum,
                                                   float* __restrict__ partial_s)
{
    const int b     = blockIdx.y;
    const int chunk = blockIdx.x;
    const int tid   = threadIdx.x;
    const int wave  = tid >> 6;
    const int lane  = tid & 63;
    const int h0    = lane >> 2;
    const int h1    = h0 + 16;
    const int dq    = (lane & 3) << 2;

    float4 vA = {0.f,0.f,0.f,0.f}, vB = {0.f,0.f,0.f,0.f};
    if (ADD_DOT) {
        vA = *(const float4*)(vsum + b*HD_ + h0*D_ + dq);
        vB = *(const float4*)(vsum + b*HD_ + h1*D_ + dq);
    }

    float4 accA = {0.f,0.f,0.f,0.f};
    float4 accB = {0.f,0.f,0.f,0.f};
    const int l0 = chunk*FB_LCH + wave*(FB_LCH/4);

    for (int j = 0; j < FB_LCH/4; ++j) {
        const int l = l0 + j;
        const float* up = u + ((size_t)b*NL_ + l)*HD_;
        const float4 a  = *(const float4*)(up + 4*lane);
        const float4 bq = *(const float4*)(up + 256 + 4*lane);

        float la = blog[l*NH_ + h0];
        float lb = blog[l*NH_ + h1];

        if (ADD_DOT) {
            float da = a.x*vA.x + a.y*vA.y + a.z*vA.z + a.w*vA.w;
            float db = bq.x*vB.x + bq.y*vB.y + bq.z*vB.z + bq.w*vB.w;
            da += __shfl_xor(da, 1); da += __shfl_xor(da, 2);
            db += __shfl_xor(db, 1); db += __shfl_xor(db, 2);
            la += da; lb += db;
        }

        float m = fmaxf(la, lb);
        #pragma unroll
        for (int off = 4; off < 64; off <<= 1) m = fmaxf(m, __shfl_xor(m, off));
        const float ea = __expf(la - m);
        const float eb = __expf(lb - m);
        float ssum = ea + eb;
        #pragma unroll
        for (int off = 4; off < 64; off <<= 1) ssum += __shfl_xor(ssum, off);
        const float inv = 1.0f / ssum;
        const float ca = ea * inv;
        const float cb = eb * inv;

        accA.x += ca*a.x;  accA.y += ca*a.y;  accA.z += ca*a.z;  accA.w += ca*a.w;
        accB.x += cb*bq.x; accB.y += cb*bq.y; accB.z += cb*bq.z; accB.w += cb*bq.w;
    }

    __shared__ float sred[4][HD_];
    float* dst = &sred[wave][0];
    dst[4*lane+0]     = accA.x; dst[4*lane+1]     = accA.y;
    dst[4*lane+2]     = accA.z; dst[4*lane+3]     = accA.w;
    dst[256+4*lane+0] = accB.x; dst[256+4*lane+1] = accB.y;
    dst[256+4*lane+2] = accB.z; dst[256+4*lane+3] = accB.w;
    __syncthreads();

    float r0 = sred[0][tid]     + sred[1][tid]     + sred[2][tid]     + sred[3][tid];
    float r1 = sred[0][tid+256] + sred[1][tid+256] + sred[2][tid+256] + sred[3][tid+256];
    float* pout = partial_s + ((size_t)b*FB_NCH + chunk)*HD_;
    pout[tid]       = r0;
    pout[tid + 256] = r1;
}

template<int MODE>
__global__ __launch_bounds__(512) void squash_fb(const float* __restrict__ partial_s,
                                                 float* __restrict__ vsum,
                                                 float* __restrict__ out)
{
    const int b = blockIdx.x;
    const int t = threadIdx.x;
    const float* p = partial_s + (size_t)b*FB_NCH*HD_ + t;
    float s = 0.f;
    #pragma unroll
    for (int c = 0; c < FB_NCH; ++c) s += p[c*HD_];

    float sq = s*s;
    sq += __shfl_xor(sq, 1); sq += __shfl_xor(sq, 2);
    sq += __shfl_xor(sq, 4); sq += __shfl_xor(sq, 8);

    const float scale = sq / ((1.0f + sq) * sqrtf(sq + 1e-8f));
    const float v = s * scale;

    if (MODE == 0)      vsum[b*HD_ + t]  = v;
    else if (MODE == 1) vsum[b*HD_ + t] += v;
    else                out[b*HD_ + t]   = v;
}

extern "C" void kernel_launch(void* const* d_in, const int* in_sizes, int n_in,
                              void* d_out, int out_size, void* d_ws, size_t ws_size,
                              hipStream_t stream)
{
    const float* u    = (const float*)d_in[0];   // [64][2048][32][16]
    const float* blog = (const float*)d_in[1];   // [2048][32]
    float* out        = (float*)d_out;           // [64][32][16]

    // ws layout: [pA 2MB][pB 2MB][vG1 128KB][vG2 128KB][u16 128MB]
    float*  pA  = (float*)d_ws;
    float*  pB  = pA  + (size_t)B_*NCH*HD_;
    float*  vG1 = pB  + (size_t)B_*NCH*HD_;
    float*  vG2 = vG1 + (size_t)B_*HD_;
    __half* u16 = (__half*)(vG2 + (size_t)B_*HD_);
    const size_t need = ((size_t)2*B_*NCH*HD_ + (size_t)2*B_*HD_)*sizeof(float)
                      + (size_t)B_*NL_*HD_*sizeof(__half);

    if (ws_size >= need) {
        dim3 grid(NCH, B_);
        pass0_kernel<<<grid, 256, 0, stream>>>(u, blog, u16, pA);
        pass16_kernel<1><<<grid, 256, 0, stream>>>(u16, blog, vG2 /*unused*/, vG1, pA, pB);
        pass16_kernel<2><<<grid, 256, 0, stream>>>(u16, blog, vG1, vG2, pB, pA);
        pass16_kernel<3><<<grid, 256, 0, stream>>>(u16, blog, vG2, vG1 /*unused*/, pA, pB);
        squash_final<<<B_, 512, 0, stream>>>(pB, out);
    } else {
        // fallback: f32 passes (needs only 4.2 MB of ws)
        float* partial_s = (float*)d_ws;
        float* vsum      = partial_s + (size_t)B_*FB_NCH*HD_;
        dim3 grid(FB_NCH, B_);

        pass_kernel<false><<<grid, 256, 0, stream>>>(u, blog, vsum, partial_s);
        squash_fb<0><<<B_, 512, 0, stream>>>(partial_s, vsum, out);

        pass_kernel<true><<<grid, 256, 0, stream>>>(u, blog, vsum, partial_s);
        squash_fb<1><<<B_, 512, 0, stream>>>(partial_s, vsum, out);

        pass_kernel<true><<<grid, 256, 0, stream>>>(u, blog, vsum, partial_s);
        squash_fb<1><<<B_, 512, 0, stream>>>(partial_s, vsum, out);

        pass_kernel<true><<<grid, 256, 0, stream>>>(u, blog, vsum, partial_s);
        squash_fb<2><<<B_, 512, 0, stream>>>(partial_s, vsum, out);
    }
}